// Round 10
// baseline (204.227 us; speedup 1.0000x reference)
//
#include <hip/hip_runtime.h>
#include <math.h>

// Planar normalizing flow, B=524288 rows, D=64, F=32.
// Two-kernel split of the 3-phase small-state form:
//   nf_ab: c = x.W^T (phase A), triangular h recurrence (phase B), logdet.
//          h stashed into the first 32 floats of each row's z-slot in d_out.
//   nf_c : z = x + Uhat^T h (phase C), reading h from the z-slot and
//          overwriting it (same thread, aliased pointer -> ordered).
// Why: r9 proved the 64-float z-carry is ALWAYS parked in AGPRs/scratch
// (VGPR_Count=40 under (256) and (256,2) alike; 45MB spill). r6's 3-phase
// form allocates honestly (32-float state) but fused all phases: 20.7KB
// param s_loads (> ~16KB K$) + cross-phase unroll bloat -> occ 29%, 135us.
// Split kernels: 12KB / 8KB param sets (K$-resident), tiny state each.

#define NF_D 64
#define NF_F 32

typedef float f4 __attribute__((ext_vector_type(4)));

// wsbuf layout (floats): wt[64][32] | Gt[32][32] | uhat[32][64] | wuh[32]
#define W_WT   0
#define W_GT   2048
#define W_UH   3072
#define W_WUH  5120
#define W_TOT  5152

// --- precompute: u_hat, wuh, W^T, G -------------------------------------
__global__ void nf_precompute(const float* __restrict__ us,
                              const float* __restrict__ ws,
                              float* __restrict__ wsbuf) {
  __shared__ float s_u[NF_F][NF_D];
  int t = threadIdx.x;
  if (t < NF_F) {
    const float* u = us + t * NF_D;
    const float* w = ws + t * NF_D;
    float wu = 0.f, n2 = 0.f;
    for (int d = 0; d < NF_D; ++d) {
      wu = fmaf(u[d], w[d], wu);
      n2 = fmaf(w[d], w[d], n2);
    }
    float sp = fmaxf(wu, 0.f) + log1pf(expf(-fabsf(wu)));  // softplus
    float coef = (sp - 1.f - wu) / sqrtf(n2);
    for (int d = 0; d < NF_D; ++d) {
      float uh = fmaf(coef, w[d], u[d]);
      s_u[t][d] = uh;
      wsbuf[W_UH + t * NF_D + d] = uh;
    }
    wsbuf[W_WUH + t] = fmaf(coef, n2, wu);       // w_t . u_hat_t
  }
  __syncthreads();
  for (int i = t; i < NF_D * NF_F; i += 256) {   // wt[d][f] = ws[f][d]
    int d = i / NF_F, f = i % NF_F;
    wsbuf[W_WT + i] = ws[f * NF_D + d];
  }
  for (int i = t; i < NF_F * NF_F; i += 256) {   // Gt[f][g] = u_hat_g . w_f
    int f = i / NF_F, g = i % NF_F;
    float s = 0.f;
    if (g < f) {
      const float* w = ws + f * NF_D;
      for (int d = 0; d < NF_D; ++d) s = fmaf(s_u[g][d], w[d], s);
    }
    wsbuf[W_GT + i] = s;                         // zero-padded for g >= f
  }
}

// tanh(x) = 1 - 2/(e^{2x}+1); hardware exp2/rcp; saturates to +-1.
__device__ __forceinline__ float fast_tanh(float x) {
  float e = __builtin_amdgcn_exp2f(x * 2.885390081777927f); // 2*log2(e)
  return 1.f - 2.f * __builtin_amdgcn_rcpf(e + 1.f);
}

// --- kernel AB: c = x.W^T -> h recurrence -> stash h, write logdet -------
__global__ __launch_bounds__(256) void nf_ab(
    const float* __restrict__ x,
    const float* __restrict__ bs,
    const float* __restrict__ wsbuf,
    float* __restrict__ zout,        // h stashed at [row*64, row*64+32)
    float* __restrict__ out_ld,
    int B) {
  const float* __restrict__ wt  = wsbuf + W_WT;
  const float* __restrict__ Gt  = wsbuf + W_GT;
  const float* __restrict__ wuh = wsbuf + W_WUH;
  int row = blockIdx.x * blockDim.x + threadIdx.x;
  if (row >= B) return;
  const f4* __restrict__ xv = reinterpret_cast<const f4*>(x + (size_t)row * NF_D);

  // Phase A: c[f] = x . w_f via transposed wt (wave-uniform s_loads, 8KB)
  f4 c[NF_F / 4];
  #pragma unroll
  for (int q = 0; q < NF_F / 4; ++q) c[q] = (f4)(0.f);
  #pragma unroll 2
  for (int dc = 0; dc < NF_D / 4; ++dc) {
    f4 xd = xv[dc];
    #pragma unroll
    for (int j = 0; j < 4; ++j) {
      const f4* __restrict__ wr =
          reinterpret_cast<const f4*>(wt + (dc * 4 + j) * NF_F);
      #pragma unroll
      for (int q = 0; q < NF_F / 4; ++q)
        c[q] += wr[q] * xd[j];               // v_pk_fma_f32
    }
  }

  // Phase B: triangular recurrence, h overwrites c (Gt: 4KB s_loads)
  float ldp = 1.f;
  #pragma unroll
  for (int f = 0; f < NF_F; ++f) {
    const f4* __restrict__ g4 = reinterpret_cast<const f4*>(Gt + f * NF_F);
    f4 a = (f4)(0.f);
    #pragma unroll
    for (int q = 0; q < (f + 3) / 4; ++q)    // zero-padded triangular
      a += g4[q] * c[q];
    float s = c[f / 4][f % 4] + bs[f] + ((a.x + a.y) + (a.z + a.w));
    float hf = fast_tanh(s);
    ldp *= fmaf(fmaf(-hf, hf, 1.f), wuh[f], 1.f);
    c[f / 4][f % 4] = hf;                    // h replaces c
  }

  f4* __restrict__ hv = reinterpret_cast<f4*>(zout + (size_t)row * NF_D);
  #pragma unroll
  for (int q = 0; q < NF_F / 4; ++q) hv[q] = c[q];  // stash h
  out_ld[row] = __builtin_amdgcn_logf(fabsf(ldp)) * 0.6931471805599453f;
}

// --- kernel C: z = x + Uhat^T h (h read from z-slot, then overwritten) ---
__global__ __launch_bounds__(256) void nf_c(
    const float* __restrict__ x,
    const float* __restrict__ wsbuf,
    float* zbuf,                    // NOT restrict: aliased h-read/z-write
    int B) {
  const float* __restrict__ uh = wsbuf + W_UH;
  int row = blockIdx.x * blockDim.x + threadIdx.x;
  if (row >= B) return;
  float* zr = zbuf + (size_t)row * NF_D;

  f4 h[NF_F / 4];
  const f4* hv = reinterpret_cast<const f4*>(zr);
  #pragma unroll
  for (int q = 0; q < NF_F / 4; ++q) h[q] = hv[q];   // load h fully first

  const f4* __restrict__ xv = reinterpret_cast<const f4*>(x + (size_t)row * NF_D);
  f4* ov = reinterpret_cast<f4*>(zr);
  #pragma unroll 2
  for (int dc = 0; dc < NF_D / 4; ++dc) {
    f4 acc = xv[dc];                          // x re-read: L3-warm
    #pragma unroll
    for (int f = 0; f < NF_F; ++f)
      acc += *reinterpret_cast<const f4*>(uh + f * NF_D + dc * 4)
             * h[f / 4][f % 4];               // uhat: 8KB K$-resident
    ov[dc] = acc;
  }
}

extern "C" void kernel_launch(void* const* d_in, const int* in_sizes, int n_in,
                              void* d_out, int out_size, void* d_ws, size_t ws_size,
                              hipStream_t stream) {
  const float* x    = (const float*)d_in[0];
  const float* us   = (const float*)d_in[1];
  const float* ws_p = (const float*)d_in[2];
  const float* bs   = (const float*)d_in[3];
  const int B = in_sizes[0] / NF_D;

  float* wsbuf = (float*)d_ws;   // W_TOT floats ~ 20.6 KB
  float* out   = (float*)d_out;  // z [B*64] then sum_log_det [B]

  nf_precompute<<<1, 256, 0, stream>>>(us, ws_p, wsbuf);
  const int block = 256;
  const int grid = (B + block - 1) / block;
  nf_ab<<<grid, block, 0, stream>>>(x, bs, wsbuf, out,
                                    out + (size_t)B * NF_D, B);
  nf_c<<<grid, block, 0, stream>>>(x, wsbuf, out, B);
}